// Round 3
// baseline (308.281 us; speedup 1.0000x reference)
//
#include <hip/hip_runtime.h>
#include <math.h>

#define NPTS  50000
#define NSP   4000
#define NGRP  1000           // NSP/4 candidate quads
#define NW    4              // waves per 64-point group
#define QW    (NGRP / NW)    // 250 quads per wave
#define KNN   11
#define BIG   3.4e38f
#define SEGCAP 512           // per-wave shortlist capacity (flush threshold SEGCAP-256)
#define SEGPAD 8
#define SEGSTR (SEGCAP + SEGPAD)
#define GRIDC 32
#define NKEY  65536          // 2 batches * 32^3 cells

#define MED3(a,b,c) __builtin_amdgcn_fmed3f((a),(b),(c))

// Static scratch: counting-sort hist/offsets + sorted points.
__device__ unsigned g_hist[NKEY];
__device__ float4   g_sorted[2 * NPTS];   // (x,y,z, orig_idx_bits)

static __device__ __forceinline__ unsigned spread5(unsigned v) {
    return (v & 1u) | ((v & 2u) << 2) | ((v & 4u) << 4) |
           ((v & 8u) << 6) | ((v & 16u) << 8);
}

static __device__ __forceinline__ unsigned cell_key(int b, float x, float y, float z) {
    int gx = (int)floorf((x + 4.0f) * 4.0f);
    int gy = (int)floorf((y + 4.0f) * 4.0f);
    int gz = (int)floorf((z + 4.0f) * 4.0f);
    gx = min(max(gx, 0), GRIDC - 1);
    gy = min(max(gy, 0), GRIDC - 1);
    gz = min(max(gz, 0), GRIDC - 1);
    unsigned m = spread5((unsigned)gx) | (spread5((unsigned)gy) << 1) |
                 (spread5((unsigned)gz) << 2);
    return ((unsigned)b << 15) | m;
}

__global__ void k_zero() {
    int t = blockIdx.x * 256 + threadIdx.x;
    if (t < NKEY) g_hist[t] = 0u;
}

__global__ void k_hist(const float* __restrict__ pts) {
    int n = blockIdx.x * 256 + threadIdx.x;
    if (n >= 2 * NPTS) return;
    const float* p = pts + (size_t)n * 3;
    int b = (n >= NPTS) ? 1 : 0;
    atomicAdd(&g_hist[cell_key(b, p[0], p[1], p[2])], 1u);
}

__global__ void k_scan() {
    __shared__ unsigned part[1024];
    const int t = threadIdx.x;
    const unsigned base = (unsigned)blockIdx.x * 32768u + (unsigned)t * 32u;
    unsigned s = 0;
#pragma unroll
    for (int j = 0; j < 32; ++j) s += g_hist[base + j];
    part[t] = s;
    __syncthreads();
    for (int off = 1; off < 1024; off <<= 1) {
        unsigned v = (t >= off) ? part[t - off] : 0u;
        __syncthreads();
        part[t] += v;
        __syncthreads();
    }
    unsigned run = (unsigned)blockIdx.x * (unsigned)NPTS + part[t] - s;
#pragma unroll
    for (int j = 0; j < 32; ++j) {
        unsigned h = g_hist[base + j];
        g_hist[base + j] = run;
        run += h;
    }
}

__global__ void k_scatter(const float* __restrict__ pts) {
    int n = blockIdx.x * 256 + threadIdx.x;
    if (n >= 2 * NPTS) return;
    const float* p = pts + (size_t)n * 3;
    int b = (n >= NPTS) ? 1 : 0;
    float x = p[0], y = p[1], z = p[2];
    unsigned dst = atomicAdd(&g_hist[cell_key(b, x, y, z)], 1u);
    if (dst < 2u * NPTS)
        g_sorted[dst] = make_float4(x, y, z, __uint_as_float((unsigned)(n - b * NPTS)));
}

static __device__ __forceinline__ float wred_min(float v) {
#pragma unroll
    for (int off = 32; off > 0; off >>= 1) v = fminf(v, __shfl_xor(v, off, 64));
    return v;
}
static __device__ __forceinline__ float sred_min16(float v) {
#pragma unroll
    for (int off = 8; off > 0; off >>= 1) v = fminf(v, __shfl_xor(v, off, 64));
    return v;
}
static __device__ __forceinline__ float sred_max16(float v) {
#pragma unroll
    for (int off = 8; off > 0; off >>= 1) v = fmaxf(v, __shfl_xor(v, off, 64));
    return v;
}

// Block = 4 waves x one 64-point Morton group. Each wave filters its QUARTER of the
// candidates into its own LDS segment via a UNION-OF-4-SUB-BOX test (16-lane sub-groups:
// tighter radii than the group box), chains it (exact med3 top-11), merges the 4 per-wave
// lists (exact union top-11), then pass B computes the edge distance.
// Overflow is handled by flush-resume chunking: cost is proportional to the admissible
// count, never to the full candidate set. All bounds are provably conservative:
//   p in box_j, s in top-11(p)  =>  boxdist(s,box_j) <= d(p,s) <= sqrt(m11_j) + R_j.
__global__ __launch_bounds__(256, 3) void voronoi_kernel(
    const float* __restrict__ spts,   // (2, NSP, 3)
    float* __restrict__ out)          // (2, NPTS)
{
    __shared__ float4 sl[NW * SEGSTR];      // 33.3 KiB shortlist segments
    __shared__ float  lds_d[NW][64][13];    // 13.3 KiB merge lists (stride 13 coprime 32)
    __shared__ int    lds_i[NW][64];
    __shared__ float  lds_b[NW][64];
    __shared__ float  lds_m[NW][4];         // per-wave per-sub m11

    const int b    = blockIdx.y;
    const int lane = threadIdx.x & 63;
    const int wq   = threadIdx.x >> 6;      // wave id = candidate quarter (wave-uniform)
    int pi = blockIdx.x * 64 + lane;
    const bool valid = (pi < NPTS);
    if (!valid) pi = NPTS - 1;              // clamp; lanes stay active

    const float4 P = g_sorted[(size_t)b * NPTS + pi];
    const float px = P.x, py = P.y, pz = P.z;
    const unsigned orig = __float_as_uint(P.w);

    // ---- per-16-lane sub-bbox + center + radius (exact regardless of sort quality) ----
    const float smnx = sred_min16(px), smxx = sred_max16(px);
    const float smny = sred_min16(py), smxy = sred_max16(py);
    const float smnz = sred_min16(pz), smxz = sred_max16(pz);
    const float scx = 0.5f * (smnx + smxx);
    const float scy = 0.5f * (smny + smxy);
    const float scz = 0.5f * (smnz + smxz);
    const float sR = sqrtf(sred_max16(
        fmaf(px - scx, px - scx, fmaf(py - scy, py - scy, (pz - scz) * (pz - scz)))));

    // broadcast all 4 sub-boxes to every lane
#define BC(v, j) __shfl((v), (j) * 16, 64)
    const float b0nx = BC(smnx,0), b0xx = BC(smxx,0), b0ny = BC(smny,0),
                b0xy = BC(smxy,0), b0nz = BC(smnz,0), b0xz = BC(smxz,0),
                c0x = BC(scx,0), c0y = BC(scy,0), c0z = BC(scz,0), R0 = BC(sR,0);
    const float b1nx = BC(smnx,1), b1xx = BC(smxx,1), b1ny = BC(smny,1),
                b1xy = BC(smxy,1), b1nz = BC(smnz,1), b1xz = BC(smxz,1),
                c1x = BC(scx,1), c1y = BC(scy,1), c1z = BC(scz,1), R1 = BC(sR,1);
    const float b2nx = BC(smnx,2), b2xx = BC(smxx,2), b2ny = BC(smny,2),
                b2xy = BC(smxy,2), b2nz = BC(smnz,2), b2xz = BC(smxz,2),
                c2x = BC(scx,2), c2y = BC(scy,2), c2z = BC(scz,2), R2 = BC(sR,2);
    const float b3nx = BC(smnx,3), b3xx = BC(smxx,3), b3ny = BC(smny,3),
                b3xy = BC(smxy,3), b3nz = BC(smnz,3), b3xz = BC(smxz,3),
                c3x = BC(scx,3), c3y = BC(scy,3), c3z = BC(scz,3), R3 = BC(sR,3);

    const float4* __restrict__ spq = (const float4*)(spts + (size_t)b * NSP * 3);
    const int g0 = wq * QW, g1 = g0 + QW;

    // ---- D_ub scan: per-lane min dist^2 to each of the 4 sub-centers (disjoint sets) ----
    float v0 = BIG, v1 = BIG, v2 = BIG, v3 = BIG;
    for (int k0 = g0; k0 < g1; k0 += 64) {
        const int g  = k0 + lane;
        const int gc = (g < g1) ? g : (g1 - 1);
        const float4 q0 = spq[3 * gc + 0];
        const float4 q1 = spq[3 * gc + 1];
        const float4 q2 = spq[3 * gc + 2];
        float t0 = BIG, t1 = BIG, t2 = BIG, t3 = BIG;
#define DACC(sx, sy, sz) { \
        float dx, dy, dz; \
        dx=(sx)-c0x; dy=(sy)-c0y; dz=(sz)-c0z; t0=fminf(t0, fmaf(dx,dx,fmaf(dy,dy,dz*dz))); \
        dx=(sx)-c1x; dy=(sy)-c1y; dz=(sz)-c1z; t1=fminf(t1, fmaf(dx,dx,fmaf(dy,dy,dz*dz))); \
        dx=(sx)-c2x; dy=(sy)-c2y; dz=(sz)-c2z; t2=fminf(t2, fmaf(dx,dx,fmaf(dy,dy,dz*dz))); \
        dx=(sx)-c3x; dy=(sy)-c3y; dz=(sz)-c3z; t3=fminf(t3, fmaf(dx,dx,fmaf(dy,dy,dz*dz))); }
        DACC(q0.x, q0.y, q0.z);
        DACC(q0.w, q1.x, q1.y);
        DACC(q1.z, q1.w, q2.x);
        DACC(q2.y, q2.z, q2.w);
        if (g < g1) { v0 = fminf(v0, t0); v1 = fminf(v1, t1);
                      v2 = fminf(v2, t2); v3 = fminf(v3, t3); }
    }

    // ---- 11 extract-min rounds, 4 streams: m11_j >= d11(c_j)^2 (disjoint lane-mins) ----
    float m0 = 0.f, m1 = 0.f, m2 = 0.f, m3 = 0.f;
#pragma unroll
    for (int t = 0; t < KNN; ++t) {
        m0 = wred_min(v0); v0 = (v0 == m0) ? BIG : v0;
        m1 = wred_min(v1); v1 = (v1 == m1) ? BIG : v1;
        m2 = wred_min(v2); v2 = (v2 == m2) ? BIG : v2;
        m3 = wred_min(v3); v3 = (v3 == m3) ? BIG : v3;
    }
    if (lane == 0) { lds_m[wq][0] = m0; lds_m[wq][1] = m1;
                     lds_m[wq][2] = m2; lds_m[wq][3] = m3; }
    __syncthreads();
    float M0 = BIG, M1 = BIG, M2 = BIG, M3 = BIG;   // min over the 4 waves: tighter, valid
#pragma unroll
    for (int q = 0; q < NW; ++q) {
        M0 = fminf(M0, lds_m[q][0]); M1 = fminf(M1, lds_m[q][1]);
        M2 = fminf(M2, lds_m[q][2]); M3 = fminf(M3, lds_m[q][3]);
    }
    const float Tr0 = sqrtf(M0) + R0; const float T0 = Tr0*Tr0*1.0004f + 1e-12f;
    const float Tr1 = sqrtf(M1) + R1; const float T1 = Tr1*Tr1*1.0004f + 1e-12f;
    const float Tr2 = sqrtf(M2) + R2; const float T2 = Tr2*Tr2*1.0004f + 1e-12f;
    const float Tr3 = sqrtf(M3) + R3; const float T3 = Tr3*Tr3*1.0004f + 1e-12f;

#define BOXD2(sx,sy,sz, nx,xx,ny,xy,nz,xz) \
    (fmaf(MED3((sx),(nx),(xx))-(sx), MED3((sx),(nx),(xx))-(sx), \
     fmaf(MED3((sy),(ny),(xy))-(sy), MED3((sy),(ny),(xy))-(sy), \
          (MED3((sz),(nz),(xz))-(sz)) * (MED3((sz),(nz),(xz))-(sz)))))
#define ADM4(sx, sy, sz) \
    ((BOXD2(sx,sy,sz, b0nx,b0xx,b0ny,b0xy,b0nz,b0xz) <= T0) || \
     (BOXD2(sx,sy,sz, b1nx,b1xx,b1ny,b1xy,b1nz,b1xz) <= T1) || \
     (BOXD2(sx,sy,sz, b2nx,b2xx,b2ny,b2xy,b2nz,b2xz) <= T2) || \
     (BOXD2(sx,sy,sz, b3nx,b3xx,b3ny,b3xy,b3nz,b3xz) <= T3))

    const int segbase = wq * SEGSTR;
    unsigned cnt = 0;

    auto padseg = [&]() {                      // 8 sentinels cover round-up + prefetch
        if (lane < SEGPAD)
            sl[segbase + (int)cnt + lane] =
                make_float4(1e18f, 1e18f, 1e18f, __uint_as_float(0x7fffffffu));
    };

#define PUSH(sx, sy, sz, ok, idx) { \
        const unsigned long long msk = __ballot(ok); \
        if (ok) { \
            const unsigned pos = cnt + \
                __builtin_amdgcn_mbcnt_hi((unsigned)(msk >> 32), \
                    __builtin_amdgcn_mbcnt_lo((unsigned)msk, 0u)); \
            sl[segbase + (int)pos] = \
                make_float4((sx), (sy), (sz), __uint_as_float((unsigned)(idx))); \
        } \
        cnt += (unsigned)__popcll(msk); }

    // Flush-resume chunked build: space for a full 64-quad batch (256 cands) is
    // guaranteed before each batch, so PUSH never needs a bounds check and no
    // candidate is ever dropped. consume(cnt) is called on flush and at the end.
    auto run_pass = [&](auto&& consume) -> bool {
        bool of = false;
        cnt = 0;
        for (int k0 = g0; k0 < g1; k0 += 64) {
            if (cnt > (unsigned)(SEGCAP - 256)) {       // wave-uniform
                padseg(); consume(cnt); cnt = 0; of = true;
            }
            const int g  = k0 + lane;
            const int gc = (g < g1) ? g : (g1 - 1);
            const bool in = (g < g1);
            const float4 q0 = spq[3 * gc + 0];
            const float4 q1 = spq[3 * gc + 1];
            const float4 q2 = spq[3 * gc + 2];
            const bool a0 = in && ADM4(q0.x, q0.y, q0.z);
            const bool a1 = in && ADM4(q0.w, q1.x, q1.y);
            const bool a2 = in && ADM4(q1.z, q1.w, q2.x);
            const bool a3 = in && ADM4(q2.y, q2.z, q2.w);
            PUSH(q0.x, q0.y, q0.z, a0, 4 * gc + 0);
            PUSH(q0.w, q1.x, q1.y, a1, 4 * gc + 1);
            PUSH(q1.z, q1.w, q2.x, a2, 4 * gc + 2);
            PUSH(q2.y, q2.z, q2.w, a3, 4 * gc + 3);
        }
        padseg(); consume(cnt);
        return of;
    };

    // ---- pass A: exact top-11 med3 chain over shortlist chunks ----
    float d0 = BIG, d1 = BIG, d2 = BIG, d3 = BIG, d4 = BIG, d5 = BIG,
          d6 = BIG, d7 = BIG, d8 = BIG, d9 = BIG, d10 = BIG;
    int i0 = 0x7fffffff;

#define CHAIN(nd, jj) { \
        if (__ballot((nd) < d10)) { \
            d10 = MED3(d9, d10, (nd)); \
            d9  = MED3(d8, d9,  (nd)); \
            d8  = MED3(d7, d8,  (nd)); \
            d7  = MED3(d6, d7,  (nd)); \
            d6  = MED3(d5, d6,  (nd)); \
            d5  = MED3(d4, d5,  (nd)); \
            d4  = MED3(d3, d4,  (nd)); \
            d3  = MED3(d2, d3,  (nd)); \
            d2  = MED3(d1, d2,  (nd)); \
            d1  = MED3(d0, d1,  (nd)); \
            i0  = ((nd) < d0) ? (jj) : i0; \
            d0  = fminf(d0, (nd)); \
        } }
#define CANDA(c) { \
        const float dx = px - (c).x, dy = py - (c).y, dz = pz - (c).z; \
        const float nd = fmaf(dx, dx, fmaf(dy, dy, dz * dz)); \
        const int jj = (int)__float_as_uint((c).w); \
        CHAIN(nd, jj); }

    auto chainA = [&](unsigned n) {
        if (n == 0u) return;
        float4 e0 = sl[segbase + 0], e1 = sl[segbase + 1],
               e2 = sl[segbase + 2], e3 = sl[segbase + 3];
        for (unsigned k = 0; k < n; k += 4) {           // 4-deep ds_read pipeline
            const float4 n0 = sl[segbase + (int)k + 4];
            const float4 n1 = sl[segbase + (int)k + 5];
            const float4 n2 = sl[segbase + (int)k + 6];
            const float4 n3 = sl[segbase + (int)k + 7];
            CANDA(e0); CANDA(e1); CANDA(e2); CANDA(e3);
            e0 = n0; e1 = n1; e2 = n2; e3 = n3;
        }
    };

    const bool ovfA = run_pass(chainA);
    const unsigned cntA = cnt;                 // valid shortlist size iff !ovfA

    // ---- publish + exact union merge across the 4 waves ----
    lds_d[wq][lane][0]  = d0;  lds_d[wq][lane][1]  = d1;
    lds_d[wq][lane][2]  = d2;  lds_d[wq][lane][3]  = d3;
    lds_d[wq][lane][4]  = d4;  lds_d[wq][lane][5]  = d5;
    lds_d[wq][lane][6]  = d6;  lds_d[wq][lane][7]  = d7;
    lds_d[wq][lane][8]  = d8;  lds_d[wq][lane][9]  = d9;
    lds_d[wq][lane][10] = d10;
    lds_i[wq][lane] = i0;
    __syncthreads();

    float gb = BIG; int gi = 0x7fffffff;
#pragma unroll
    for (int q = 0; q < NW; ++q) {
        const float dq = lds_d[q][lane][0];
        const int   iq = lds_i[q][lane];
        const bool take = (dq < gb) || (dq == gb && iq < gi);
        gb = take ? dq : gb;
        gi = take ? iq : gi;
    }
#define INS(v) { \
        d10 = MED3(d9, d10, (v)); \
        d9  = MED3(d8, d9,  (v)); \
        d8  = MED3(d7, d8,  (v)); \
        d7  = MED3(d6, d7,  (v)); \
        d6  = MED3(d5, d6,  (v)); \
        d5  = MED3(d4, d5,  (v)); \
        d4  = MED3(d3, d4,  (v)); \
        d3  = MED3(d2, d3,  (v)); \
        d2  = MED3(d1, d2,  (v)); \
        d1  = MED3(d0, d1,  (v)); \
        d0  = fminf(d0, (v)); }
#pragma unroll
    for (int q = 0; q < NW; ++q) {
        if (q == wq) continue;
#pragma unroll
        for (int k = 0; k < 11; ++k) INS(lds_d[q][lane][k]);
    }
    const float d10g = d10;                 // exact union 11th-smallest
    const int   i0g  = gi;                  // exact lexicographic argmin

    // ---- pass B: edge distance over the admissible set ----
    const float* ip = spts + (size_t)b * NSP * 3 + (size_t)(unsigned)i0g * 3;
    const float ix = ip[0], iy = ip[1], iz = ip[2];
    const float vx = px - ix, vy = py - iy, vz = pz - iz;
    float best = BIG;

#define CANDB(c) { \
        const float dx = px - (c).x, dy = py - (c).y, dz = pz - (c).z; \
        const float nd = fmaf(dx, dx, fmaf(dy, dy, dz * dz)); \
        const int jj = (int)__float_as_uint((c).w); \
        const bool adm = (nd <= d10g) && (jj != i0g); \
        if (__ballot(adm)) { \
            const float ex = (c).x - ix, ey = (c).y - iy, ez = (c).z - iz; \
            const float ee = fmaf(ex, ex, fmaf(ey, ey, ez * ez)); \
            const float dt = fmaf(vx, ex, fmaf(vy, ey, vz * ez)); \
            const float u  = fmaf(-0.5f, ee, dt); \
            const float t2 = u * u * __builtin_amdgcn_rcpf(ee); \
            best = adm ? fminf(best, t2) : best; \
        } }

    auto scanB = [&](unsigned n) {
        if (n == 0u) return;
        float4 e0 = sl[segbase + 0], e1 = sl[segbase + 1],
               e2 = sl[segbase + 2], e3 = sl[segbase + 3];
        for (unsigned k = 0; k < n; k += 4) {
            const float4 n0 = sl[segbase + (int)k + 4];
            const float4 n1 = sl[segbase + (int)k + 5];
            const float4 n2 = sl[segbase + (int)k + 6];
            const float4 n3 = sl[segbase + (int)k + 7];
            CANDB(e0); CANDB(e1); CANDB(e2); CANDB(e3);
            e0 = n0; e1 = n1; e2 = n2; e3 = n3;
        }
    };

    if (!ovfA) {
        scanB(cntA);                        // reuse intact shortlist (own segment only)
    } else {
        (void)run_pass(scanB);              // rebuild with flush-resume (exact)
    }

    // ---- final min across the 4 waves ----
    lds_b[wq][lane] = best;
    __syncthreads();
    if (wq == 0) {
        float m = fminf(fminf(lds_b[0][lane], lds_b[1][lane]),
                        fminf(lds_b[2][lane], lds_b[3][lane]));
        if (valid) out[(size_t)b * NPTS + orig] = m;
    }
}

extern "C" void kernel_launch(void* const* d_in, const int* in_sizes, int n_in,
                              void* d_out, int out_size, void* d_ws, size_t ws_size,
                              hipStream_t stream) {
    (void)in_sizes; (void)n_in; (void)d_ws; (void)ws_size; (void)out_size;
    const float* pts  = (const float*)d_in[0];   // (2, 50000, 3)
    const float* spts = (const float*)d_in[1];   // (2, 4000, 3)
    float* out = (float*)d_out;                  // (2, 50000)

    k_zero   <<<dim3(NKEY / 256),            dim3(256),  0, stream>>>();
    k_hist   <<<dim3((2 * NPTS + 255)/256),  dim3(256),  0, stream>>>(pts);
    k_scan   <<<dim3(2),                     dim3(1024), 0, stream>>>();
    k_scatter<<<dim3((2 * NPTS + 255)/256),  dim3(256),  0, stream>>>(pts);
    voronoi_kernel<<<dim3((NPTS + 63)/64, 2), dim3(256), 0, stream>>>(spts, out);
}